// Round 1
// baseline (107.948 us; speedup 1.0000x reference)
//
#include <hip/hip_runtime.h>

#define B_TOTAL 524288
#define HID 128

__global__ __launch_bounds__(256, 8) void ode_kernel(
    const float* __restrict__ t,
    const float* __restrict__ u,
    const float* __restrict__ p,
    const float* __restrict__ W1,
    const float* __restrict__ b1,
    const float* __restrict__ W2,
    const float* __restrict__ b2,
    float* __restrict__ out)
{
    // Packed per-hidden-unit weights: [W1col(5), b1, W2row(2)] = 8 floats * 128 = 4KB.
    // All lanes read the SAME address each iteration -> LDS broadcast, no bank conflicts.
    __shared__ float wpk[HID * 8];
    const int tid = threadIdx.x;
    for (int j = tid; j < HID; j += 256) {
        wpk[j * 8 + 0] = W1[0 * HID + j];
        wpk[j * 8 + 1] = W1[1 * HID + j];
        wpk[j * 8 + 2] = W1[2 * HID + j];
        wpk[j * 8 + 3] = W1[3 * HID + j];
        wpk[j * 8 + 4] = W1[4 * HID + j];
        wpk[j * 8 + 5] = b1[j];
        wpk[j * 8 + 6] = W2[j * 2 + 0];
        wpk[j * 8 + 7] = W2[j * 2 + 1];
    }
    __syncthreads();

    const int row = blockIdx.x * 256 + tid;   // grid sized exactly to B_TOTAL

    // ---- load u row (10 f32) as 5x float2 (rows are 40B, 8B aligned) ----
    const float2* u2 = reinterpret_cast<const float2*>(u + (size_t)row * 10);
    float2 ua = u2[0], ub = u2[1], uc = u2[2], ud = u2[3], ue = u2[4];
    const float Qmt = ua.x, Qav = ua.y, Qtc = ub.x, Qpv = ub.y;
    const float Vlv = uc.x, Vao = uc.y, Vvc = ud.x, Vrv = ud.y;
    const float Vpa = ue.x, Vpu = ue.y;

    // ---- e = exp(-80*(mod(t,0.75)-0.375)^2); t in [0,1) so mod is a cond-subtract ----
    const float tv = t[row];
    const float m  = (tv >= 0.75f) ? (tv - 0.75f) : tv;
    const float dd = m - 0.375f;
    const float e  = __expf(-80.0f * dd * dd);

    // ---- MLP: z = tanh([Vlv,Vao,Vvc,Vrv,Vpa] @ W1 + b1) @ W2 + b2 ----
    float z0 = b2[0], z1 = b2[1];
#pragma unroll 4
    for (int j = 0; j < HID; ++j) {
        const float* w = &wpk[j * 8];
        float a = w[5];
        a = fmaf(Vlv, w[0], a);
        a = fmaf(Vao, w[1], a);
        a = fmaf(Vvc, w[2], a);
        a = fmaf(Vrv, w[3], a);
        a = fmaf(Vpa, w[4], a);
        // tanh(a) = 1 - 2/(exp(2a)+1); overflow-safe (exp->inf => 1.0 exactly)
        const float e2 = __expf(2.0f * a);
        const float th = 1.0f - 2.0f * __builtin_amdgcn_rcpf(e2 + 1.0f);
        z0 = fmaf(th, w[6], z0);
        z1 = fmaf(th, w[7], z1);
    }
    const float Pperi = z0, Vspt = z1;

    // ---- p scalars (uniform -> s_loads) ----
    const float Elvf = p[0],  Eao = p[1],   Evc = p[2],   Ervf = p[3];
    const float Epa  = p[4],  Epu = p[5];
    const float Rmt  = p[6],  Rav = p[7],   Rsys = p[8],  Rtc = p[9];
    const float Rpv  = p[10], Rpul = p[11];
    const float Lmt  = p[12], Lav = p[13],  Ltc = p[14],  Lpv = p[15];
    const float Vdlvf = p[16], Vdao = p[17], Vdvc = p[18], Vdrvf = p[19];
    const float Vdpa  = p[20], Vdpu = p[21];
    const float P0lvf = p[22], P0rvf = p[23];
    const float lamlvf = p[24], lamrvf = p[25];
    const float V0lvf = p[27], V0rvf = p[28];
    const float Pth   = p[36];

    const float Vlvf = Vlv - Vspt;
    const float Vrvf = Vrv + Vspt;
    const float alv = fminf(lamlvf * (Vlvf - V0lvf), 88.0f);
    const float arv = fminf(lamrvf * (Vrvf - V0rvf), 88.0f);
    const float exp_lv = __expf(alv);
    const float exp_rv = __expf(arv);
    const float ome = 1.0f - e;
    const float Plvf = e * Elvf * (Vlvf - Vdlvf) + ome * P0lvf * (exp_lv - 1.0f);
    const float Prvf = e * Ervf * (Vrvf - Vdrvf) + ome * P0rvf * (exp_rv - 1.0f);
    const float Plv = Plvf + Pperi;
    const float Prv = Prvf + Pperi;
    const float Pao = Eao * (Vao - Vdao);
    const float Pvc = Evc * (Vvc - Vdvc);
    const float Ppa = fmaf(Epa, Vpa - Vdpa, Pth);
    const float Ppu = fmaf(Epu, Vpu - Vdpu, Pth);
    const float Qsys = (Pao - Pvc) / Rsys;
    const float Qpul = (Ppa - Ppu) / Rpul;

    const float du0 = ((Ppu - Plv > 0.0f) || (Qmt > 0.0f)) ? (Ppu - Plv - Qmt * Rmt) / Lmt : 0.0f;
    const float du1 = ((Plv - Pao > 0.0f) || (Qav > 0.0f)) ? (Plv - Pao - Qav * Rav) / Lav : 0.0f;
    const float du2 = ((Pvc - Prv > 0.0f) || (Qtc > 0.0f)) ? (Pvc - Prv - Qtc * Rtc) / Ltc : 0.0f;
    const float du3 = ((Prv - Ppa > 0.0f) || (Qpv > 0.0f)) ? (Prv - Ppa - Qpv * Rpv) / Lpv : 0.0f;

    const float Qmt_c = fmaxf(Qmt, 0.0f);
    const float Qav_c = fmaxf(Qav, 0.0f);
    const float Qtc_c = fmaxf(Qtc, 0.0f);
    const float Qpv_c = fmaxf(Qpv, 0.0f);
    const float du4 = Qmt_c - Qav_c;
    const float du5 = Qav_c - Qsys;
    const float du6 = Qsys - Qtc_c;
    const float du7 = Qtc_c - Qpv_c;
    const float du8 = Qpv_c - Qpul;
    const float du9 = Qpul - Qmt_c;

    float2* o2 = reinterpret_cast<float2*>(out + (size_t)row * 10);
    o2[0] = make_float2(du0, du1);
    o2[1] = make_float2(du2, du3);
    o2[2] = make_float2(du4, du5);
    o2[3] = make_float2(du6, du7);
    o2[4] = make_float2(du8, du9);
}

extern "C" void kernel_launch(void* const* d_in, const int* in_sizes, int n_in,
                              void* d_out, int out_size, void* d_ws, size_t ws_size,
                              hipStream_t stream) {
    const float* t  = (const float*)d_in[0];
    const float* u  = (const float*)d_in[1];
    const float* p  = (const float*)d_in[2];
    const float* W1 = (const float*)d_in[3];
    const float* b1 = (const float*)d_in[4];
    const float* W2 = (const float*)d_in[5];
    const float* b2 = (const float*)d_in[6];
    float* out = (float*)d_out;

    dim3 grid(B_TOTAL / 256), block(256);
    ode_kernel<<<grid, block, 0, stream>>>(t, u, p, W1, b1, W2, b2, out);
}